// Round 3
// baseline (686.697 us; speedup 1.0000x reference)
//
#include <hip/hip_runtime.h>

#define Bdim 16
#define Tdim 1024
#define Hdim 256
#define Ldim 2048

typedef __attribute__((ext_vector_type(8))) short short8;    // 8 x bf16 (4 VGPR) MFMA frag
typedef __attribute__((ext_vector_type(4))) short short4_t;  // 8B LDS store
typedef __attribute__((ext_vector_type(16))) float floatx16; // 32x32 MFMA accumulator

__device__ __forceinline__ ushort f2bf(float x) {
    union { float f; unsigned u; } v; v.f = x;
    unsigned r = v.u + 0x7fffu + ((v.u >> 16) & 1u);  // round-to-nearest-even
    return (ushort)(r >> 16);
}
__device__ __forceinline__ float bf2f(ushort u) {
    union { unsigned u; float f; } v; v.u = ((unsigned)u) << 16;
    return v.f;
}
__device__ __forceinline__ short8 pack8(float4 a, float4 b) {
    short8 r;
    r[0] = (short)f2bf(a.x); r[1] = (short)f2bf(a.y); r[2] = (short)f2bf(a.z); r[3] = (short)f2bf(a.w);
    r[4] = (short)f2bf(b.x); r[5] = (short)f2bf(b.y); r[6] = (short)f2bf(b.z); r[7] = (short)f2bf(b.w);
    return r;
}

// async global->LDS DMA, 16B per lane; dest is wave-uniform base + lane*16.
__device__ __forceinline__ void gload_lds16(const void* g, void* l) {
    __builtin_amdgcn_global_load_lds((const __attribute__((address_space(1))) unsigned*)g,
                                     (__attribute__((address_space(3))) unsigned*)l, 16, 0, 0);
}
#define VMCNT0() do { asm volatile("s_waitcnt vmcnt(0)" ::: "memory"); __builtin_amdgcn_sched_barrier(0); } while (0)
#define VMCNT4() do { asm volatile("s_waitcnt vmcnt(4)" ::: "memory"); __builtin_amdgcn_sched_barrier(0); } while (0)
#define LGKM0()  do { asm volatile("s_waitcnt lgkmcnt(0)" ::: "memory"); __builtin_amdgcn_sched_barrier(0); } while (0)

// fp32 (B,T,H) -> bf16 (B,T,H) and bf16 transposed (B,H,T). All global accesses 16B.
__global__ __launch_bounds__(256) void convert_kernel(
    const float* __restrict__ in, ushort* __restrict__ outN, ushort* __restrict__ outT) {
    __shared__ ushort lds[64][68];
    const int b = blockIdx.z, h0 = blockIdx.y * 64, t0 = blockIdx.x * 64;
    const int tid = threadIdx.x;
#pragma unroll
    for (int i = 0; i < 2; i++) {
        const int tt = tid + i * 256;
        const int r = tt >> 3, c = (tt & 7) * 8;
        const float4* src = (const float4*)(in + ((size_t)(b * Tdim + t0 + r)) * Hdim + h0 + c);
        short8 u = pack8(src[0], src[1]);
        *(short8*)(outN + ((size_t)(b * Tdim + t0 + r)) * Hdim + h0 + c) = u;
        short4_t lo = {u[0], u[1], u[2], u[3]}, hi = {u[4], u[5], u[6], u[7]};
        *(short4_t*)&lds[r][c] = lo;
        *(short4_t*)&lds[r][c + 4] = hi;
    }
    __syncthreads();
#pragma unroll
    for (int i = 0; i < 2; i++) {
        const int tt = tid + i * 256;
        const int hh = tt >> 3, c = (tt & 7) * 8;
        short8 u;
#pragma unroll
        for (int j = 0; j < 8; j++) u[j] = (short)lds[c + j][hh];
        *(short8*)(outT + ((size_t)(b * Hdim + h0 + hh)) * Tdim + t0 + c) = u;
    }
}

// One block = (b, 32 L-rows), 8 waves, 32x32x16 MFMA.
//
// v3: v2 was L2-latency bound: both pipes <9%, L2 K/V streams achieved only
// ~6.6 TB/s of the 34.5 TB/s ceiling because plain VGPR loads cap in-flight
// bytes at ~200 B/wave (64 arch VGPRs). Now K (Phase A) and V (Phase C) are
// staged wave-private through LDS via global_load_lds (zero VGPR cost, 4 KB
// in flight per wave), double-buffered with counted vmcnt (never drained to 0
// in steady state). LDS = 64 KB stage + 16 KB P-chunk dbuf = exactly 80 KB ->
// still 2 blocks/CU. Q and P use 16B-slot XOR swizzle (conflict-free-ish);
// staged K/V use layouts derived so frag reads are contiguous slot runs.
__global__ __launch_bounds__(512, 4) void attn_kernel(
    const float* __restrict__ table, const int* __restrict__ labels,
    const ushort* __restrict__ kn, const ushort* __restrict__ vt,
    float* __restrict__ logits_out, float* __restrict__ attn_out) {
    __shared__ ushort kst[8][2][2048];  // 64 KB: per-wave stage bufs (K h-chunks, then V t-chunks)
    __shared__ ushort P2[2][32][128];   // 16 KB: P chunk dbuf, slot-XOR swizzled; Q + f32 scratch alias

    const int bid = blockIdx.x;
    const int xcd = bid & 7, w = bid >> 3;     // dispatch XCD = blockIdx % 8
    const int b = xcd * 2 + (w >> 6);          // 2 batches pinned per XCD
    const int l0 = (w & 63) * 32;
    const int tid = threadIdx.x;
    const int wave = tid >> 6, lane = tid & 63;
    const int half = lane >> 5, m = lane & 31;

    // Q tile aliases P2 entirely (dead before any P write; barrier-protected).
    // Layout [32 rows][256 h], 16B slot s stored at s ^ (row&15).
    ushort (*qt)[256] = (ushort(*)[256]) & P2[0][0][0];

    // ---- stage Q: gather 32 table rows, convert bf16 -> LDS (XOR slots) ----
    {
        const int row = tid >> 4, q16 = tid & 15;
        const int lab = labels[b * Ldim + l0 + row];
        const float4* src = (const float4*)(table + (size_t)lab * Hdim + q16 * 16);
        float4 f0 = src[0], f1 = src[1], f2 = src[2], f3 = src[3];
        const int s0 = q16 * 2;
        *(short8*)&qt[row][((s0) ^ (row & 15)) * 8] = pack8(f0, f1);
        *(short8*)&qt[row][((s0 + 1) ^ (row & 15)) * 8] = pack8(f2, f3);
    }

    // ---- Phase A prologue: issue K chunks 0,1 (4 KB each: [128t][16h]) ----
    // stage inst j covers t-tile j; lane i -> t = t0s + j*32 + i/2, h = hc + (i&1)*8.
    // LDS slot j*64 + i; frag read (T,half): slot T*64 + 2m+half -> 64 contiguous slots.
    const int t0s = wave * 128;
    const ushort* kbase[4];
#pragma unroll
    for (int j = 0; j < 4; j++)
        kbase[j] = kn + ((size_t)(b * Tdim + t0s + j * 32 + (lane >> 1))) * Hdim + (lane & 1) * 8;
#pragma unroll
    for (int j = 0; j < 4; j++) gload_lds16(kbase[j], &kst[wave][0][j * 512]);
#pragma unroll
    for (int j = 0; j < 4; j++) gload_lds16(kbase[j] + 16, &kst[wave][1][j * 512]);

    __syncthreads();  // Q visible; K chunks 0,1 landed (barrier drains vmem)

    // ---- Phase A: S-strip (32 l x 128 t) per wave, 4 chains, staged K ----
    floatx16 acc[4];
#pragma unroll
    for (int nt = 0; nt < 4; nt++)
#pragma unroll
        for (int r = 0; r < 16; r++) acc[nt][r] = 0.f;
#pragma unroll
    for (int ks = 0; ks < 16; ks++) {
        if (ks == 15) { VMCNT0(); }       // last chunk: nothing newer in flight
        else if (ks > 0) { VMCNT4(); }    // chunk ks done; chunk ks+1 (4 insts) stays in flight
        const ushort* kw = &kst[wave][ks & 1][0];
        short8 af = *(const short8*)&qt[m][(((ks * 2 + half)) ^ (m & 15)) * 8];
        short8 b0 = *(const short8*)&kw[0 * 512 + (2 * m + half) * 8];
        short8 b1 = *(const short8*)&kw[1 * 512 + (2 * m + half) * 8];
        short8 b2 = *(const short8*)&kw[2 * 512 + (2 * m + half) * 8];
        short8 b3 = *(const short8*)&kw[3 * 512 + (2 * m + half) * 8];
        acc[0] = __builtin_amdgcn_mfma_f32_32x32x16_bf16(af, b0, acc[0], 0, 0, 0);
        acc[1] = __builtin_amdgcn_mfma_f32_32x32x16_bf16(af, b1, acc[1], 0, 0, 0);
        acc[2] = __builtin_amdgcn_mfma_f32_32x32x16_bf16(af, b2, acc[2], 0, 0, 0);
        acc[3] = __builtin_amdgcn_mfma_f32_32x32x16_bf16(af, b3, acc[3], 0, 0, 0);
        if (ks < 14) {
            LGKM0();  // this buf's ds_reads landed; safe to DMA-overwrite it
#pragma unroll
            for (int j = 0; j < 4; j++)
                gload_lds16(kbase[j] + (ks + 2) * 16, &kst[wave][ks & 1][j * 512]);
        }
    }

    // ---- exp + per-row sums. 32x32 C/D: row=(r&3)+8*(r>>2)+4*half, col=m ----
    float rs[16];
#pragma unroll
    for (int nt = 0; nt < 4; nt++)
#pragma unroll
        for (int r = 0; r < 16; r++) {
            float e = __expf(acc[nt][r]);
            acc[nt][r] = e;
            if (nt == 0) rs[r] = e; else rs[r] += e;
        }
#pragma unroll
    for (int s = 1; s < 32; s <<= 1)
#pragma unroll
        for (int r = 0; r < 16; r++) rs[r] += __shfl_xor(rs[r], s, 64);

    // f32 scratch aliases P2[1] (Q dead after this barrier; chunk1 written later)
    float* sc = (float*)&P2[1][0][0];      // [8][32] partial sums
    float* rinv = sc + 256;                // [32] 1/rowsum
    __syncthreads();                       // Phase A done everywhere; Q dead
    if (m == 0) {
#pragma unroll
        for (int r = 0; r < 16; r++) sc[wave * 32 + (r & 3) + 8 * (r >> 2) + 4 * half] = rs[r];
    }
    __syncthreads();
    if (tid < 32) {
        float d = 0.f;
#pragma unroll
        for (int wv = 0; wv < 8; wv++) d += sc[wv * 32 + tid];
        rinv[tid] = 1.0f / d;
    }
    __syncthreads();
    float inv[16];
#pragma unroll
    for (int r = 0; r < 16; r++) inv[r] = rinv[(r & 3) + 8 * (r >> 2) + 4 * half];

    // ---- pack exp(S) strip to bf16 pairs ----
    unsigned pk[2][16];
#pragma unroll
    for (int p = 0; p < 2; p++)
#pragma unroll
        for (int r = 0; r < 16; r++)
            pk[p][r] = (unsigned)f2bf(acc[2 * p][r]) |
                       ((unsigned)f2bf(acc[2 * p + 1][r]) << 16);

    // strip = exactly one P chunk (128t). Slot-XOR write: slot (nt*4 + m/8) ^ (row&15).
    auto write_strip = [&](int bi) {
        ushort* dst = &P2[bi][0][0];
#pragma unroll
        for (int p = 0; p < 2; p++)
#pragma unroll
            for (int r = 0; r < 16; r++) {
                const int row = (r & 3) + 8 * (r >> 2) + 4 * half;
                const int n0 = 2 * p, n1 = 2 * p + 1;
                dst[row * 128 + (((n0 * 4 + (m >> 3)) ^ (row & 15)) * 8) + (m & 7)] =
                    (ushort)(pk[p][r] & 0xffffu);
                dst[row * 128 + (((n1 * 4 + (m >> 3)) ^ (row & 15)) * 8) + (m & 7)] =
                    (ushort)(pk[p][r] >> 16);
            }
    };
    if (wave == 0) write_strip(0);

    // ---- attention out: straight from registers, normalized dword stores ----
    {
        float* dst = attn_out + ((size_t)(b * Ldim + l0)) * Tdim + wave * 128 + m;
#pragma unroll
        for (int p = 0; p < 2; p++)
#pragma unroll
            for (int r = 0; r < 16; r++) {
                const int row = (r & 3) + 8 * (r >> 2) + 4 * half;
                dst[(size_t)row * Tdim + (2 * p) * 32] =
                    bf2f((ushort)(pk[p][r] & 0xffffu)) * inv[r];
                dst[(size_t)row * Tdim + (2 * p + 1) * 32] =
                    bf2f((ushort)(pk[p][r] >> 16)) * inv[r];
            }
    }

    // ---- Phase C: logits = P.V over 8 chunks of 128t; V staged per 64t ----
    // V chunk [32h][64t] = 4 KB; lane i, inst j -> h' = j*8 + i/8, stored t-slot (i&7)^(h'&7).
    const ushort* vbase = vt + ((size_t)(b * Hdim + wave * 32 + (lane >> 3))) * Tdim +
                          ((lane & 7) ^ ((lane >> 3) & 7)) * 8;
    auto issueV = [&](int vb, int tb) {
#pragma unroll
        for (int j = 0; j < 4; j++)
            gload_lds16(vbase + (size_t)j * 8 * Tdim + tb, &kst[wave][vb][j * 512]);
    };

    issueV(0, 0);      // pc0's first V chunk; drains at the barrier below
    __syncthreads();   // chunk0 P + rowinv consumed; attn stores + vc0 drained

    floatx16 c0, c1;
#pragma unroll
    for (int r = 0; r < 16; r++) { c0[r] = 0.f; c1[r] = 0.f; }

    for (int pc = 0; pc < 8; ++pc) {
        if (pc) __syncthreads();                     // P chunk pc visible; prev-issued vc0 landed
        if (pc < 7 && wave == pc + 1) write_strip((pc + 1) & 1);
        issueV(1, pc * 128 + 64);                    // vc1: hidden under c0 compute
        const ushort* pw = &P2[pc & 1][0][0];
        const ushort* vw0 = &kst[wave][0][0];
        const ushort* vw1 = &kst[wave][1][0];
#pragma unroll
        for (int s = 0; s < 4; s++) {
            short8 a = *(const short8*)&pw[m * 128 + (((s * 2 + half) ^ (m & 15)) * 8)];
            short8 v = *(const short8*)&vw0[m * 64 + (((s * 2 + half) ^ (m & 7)) * 8)];
            c0 = __builtin_amdgcn_mfma_f32_32x32x16_bf16(a, v, c0, 0, 0, 0);
        }
        VMCNT0();                                    // vc1 residual wait
#pragma unroll
        for (int s = 0; s < 4; s++) {
            short8 a = *(const short8*)&pw[m * 128 + ((((s + 4) * 2 + half) ^ (m & 15)) * 8)];
            short8 v = *(const short8*)&vw1[m * 64 + (((s * 2 + half) ^ (m & 7)) * 8)];
            c1 = __builtin_amdgcn_mfma_f32_32x32x16_bf16(a, v, c1, 0, 0, 0);
        }
        if (pc < 7) {
            LGKM0();                                 // vw0 reads landed; safe to DMA-overwrite
            issueV(0, (pc + 1) * 128);               // next pc's vc0; lands during barrier
        }
    }

#pragma unroll
    for (int r = 0; r < 16; r++) {
        const int row = (r & 3) + 8 * (r >> 2) + 4 * half;
        logits_out[((size_t)(b * Ldim + l0 + row)) * Hdim + wave * 32 + m] =
            (c0[r] + c1[r]) * inv[r];
    }
}

extern "C" void kernel_launch(void* const* d_in, const int* in_sizes, int n_in,
                              void* d_out, int out_size, void* d_ws, size_t ws_size,
                              hipStream_t stream) {
    const float* inputs = (const float*)d_in[0];   // (B,T,H) fp32
    const int* labels   = (const int*)d_in[1];     // (B,L)
    const float* table  = (const float*)d_in[2];   // (NC+1,H) fp32
    float* out = (float*)d_out;

    ushort* kn = (ushort*)d_ws;                    // bf16 (B,T,H)
    ushort* vt = kn + (size_t)Bdim * Tdim * Hdim;  // bf16 (B,H,T)

    convert_kernel<<<dim3(Tdim / 64, Hdim / 64, Bdim), 256, 0, stream>>>(inputs, kn, vt);

    float* logits_out = out;
    float* attn_out = out + (size_t)Bdim * Ldim * Hdim;
    attn_kernel<<<Bdim * (Ldim / 32), 512, 0, stream>>>(table, labels, kn, vt,
                                                        logits_out, attn_out);
}

// Round 5
// 436.022 us; speedup vs baseline: 1.5749x; 1.5749x over previous
//
#include <hip/hip_runtime.h>

#define Bdim 16
#define Tdim 1024
#define Hdim 256
#define Ldim 2048

typedef __attribute__((ext_vector_type(8))) short short8;    // 8 x bf16 (4 VGPR) MFMA frag
typedef __attribute__((ext_vector_type(4))) short short4_t;  // 8B LDS store
typedef __attribute__((ext_vector_type(16))) float floatx16; // 32x32 MFMA accumulator

__device__ __forceinline__ ushort f2bf(float x) {
    union { float f; unsigned u; } v; v.f = x;
    unsigned r = v.u + 0x7fffu + ((v.u >> 16) & 1u);  // round-to-nearest-even
    return (ushort)(r >> 16);
}
__device__ __forceinline__ float bf2f(ushort u) {
    union { unsigned u; float f; } v; v.u = ((unsigned)u) << 16;
    return v.f;
}
__device__ __forceinline__ short8 pack8(float4 a, float4 b) {
    short8 r;
    r[0] = (short)f2bf(a.x); r[1] = (short)f2bf(a.y); r[2] = (short)f2bf(a.z); r[3] = (short)f2bf(a.w);
    r[4] = (short)f2bf(b.x); r[5] = (short)f2bf(b.y); r[6] = (short)f2bf(b.z); r[7] = (short)f2bf(b.w);
    return r;
}

// async global->LDS DMA, 16B per lane; dest = wave-uniform base + lane*16.
__device__ __forceinline__ void gload_lds16(const void* g, void* l) {
    __builtin_amdgcn_global_load_lds((const __attribute__((address_space(1))) unsigned*)g,
                                     (__attribute__((address_space(3))) unsigned*)l, 16, 0, 0);
}

// fp32 (B,T,H) -> bf16 (B,T,H) and bf16 transposed (B,H,T). All global accesses 16B.
__global__ __launch_bounds__(256) void convert_kernel(
    const float* __restrict__ in, ushort* __restrict__ outN, ushort* __restrict__ outT) {
    __shared__ ushort lds[64][68];
    const int b = blockIdx.z, h0 = blockIdx.y * 64, t0 = blockIdx.x * 64;
    const int tid = threadIdx.x;
#pragma unroll
    for (int i = 0; i < 2; i++) {
        const int tt = tid + i * 256;
        const int r = tt >> 3, c = (tt & 7) * 8;
        const float4* src = (const float4*)(in + ((size_t)(b * Tdim + t0 + r)) * Hdim + h0 + c);
        short8 u = pack8(src[0], src[1]);
        *(short8*)(outN + ((size_t)(b * Tdim + t0 + r)) * Hdim + h0 + c) = u;
        short4_t lo = {u[0], u[1], u[2], u[3]}, hi = {u[4], u[5], u[6], u[7]};
        *(short4_t*)&lds[r][c] = lo;
        *(short4_t*)&lds[r][c + 4] = hi;
    }
    __syncthreads();
#pragma unroll
    for (int i = 0; i < 2; i++) {
        const int tt = tid + i * 256;
        const int hh = tt >> 3, c = (tt & 7) * 8;
        short8 u;
#pragma unroll
        for (int j = 0; j < 8; j++) u[j] = (short)lds[c + j][hh];
        *(short8*)(outT + ((size_t)(b * Hdim + h0 + hh)) * Tdim + t0 + c) = u;
    }
}

// One block = (b, 32 L-rows), 8 waves, 32x32x16 MFMA.
//
// v4: v2 was L2-latency bound (~200 B/wave in flight, both pipes <9%). v3's
// asm-vmcnt DMA pipeline caused scratch spills + L2 thrash (FETCH 33->235 MB,
// WRITE 174->567 MB). v4 keeps the DMA staging idea but uses the proven m97
// idiom: plain __syncthreads()-clocked double buffers, NO inline asm. Each
// step: barrier; issue next 4 KB chunk via global_load_lds (lands during
// compute, drained by next barrier); consume current chunk from LDS.
// K chunks [128t][16h], V chunks [32h][64t], per-wave private. P chunks 64t,
// XOR-swizzled, produced one step ahead by owner wave. LDS = 64 KB stage +
// 16 KB Q-area (aliased post-A by P dbuf + stats) = exactly 80 KB -> 2 blk/CU.
// v4b: fix OOB staging addresses (used block index w where wave was intended;
// faulted the GPU -> "container failed twice").
__global__ __launch_bounds__(512, 4) void attn_kernel(
    const float* __restrict__ table, const int* __restrict__ labels,
    const ushort* __restrict__ kn, const ushort* __restrict__ vt,
    float* __restrict__ logits_out, float* __restrict__ attn_out) {
    __shared__ ushort stage[8][2][2048];  // 64 KB: per-wave K/V DMA dbuf (4 KB chunks)
    __shared__ ushort qarea[32][256];     // 16 KB: Q (Phase A); post-A: P dbuf + stats

    const int bid = blockIdx.x;
    const int xcd = bid & 7, w = bid >> 3;     // dispatch XCD = blockIdx % 8
    const int b = xcd * 2 + (w >> 6);          // 2 batches pinned per XCD
    const int l0 = (w & 63) * 32;
    const int tid = threadIdx.x;
    const int wave = tid >> 6, lane = tid & 63;
    const int half = lane >> 5, m = lane & 31;

    ushort (*qt)[256] = qarea;                 // Q: [32 rows][32 slots], slot s at s^(row&15)
    ushort* p2 = &qarea[0][0];                 // post-A: P dbuf [2][32 rows][8 slots] (8 KB)
    float* sc = (float*)&qarea[16][0];         // post-A: [8][32] partial row sums
    float* rinv = (float*)&qarea[18][0];       // post-A: [32] 1/rowsum

    // ---- issue K chunk 0 DMA first (overlaps Q gather latency) ----
    // K chunk hc: this wave's [128t][16h]. inst j, lane l: t = wave*128+j*32+(l&31),
    // h = hc*16+(l>>5)*8. dest slot = j*64+l (linear). Frag (nt,half) = slot
    // nt*64+half*32+m -> 32 consecutive 16B slots: conflict-free.
    const ushort* ksrc =
        kn + ((size_t)(b * Tdim + wave * 128 + (lane & 31))) * Hdim + (lane >> 5) * 8;
#pragma unroll
    for (int j = 0; j < 4; j++) gload_lds16(ksrc + j * 32 * Hdim, &stage[wave][0][j * 512]);

    // ---- stage Q: gather 32 table rows, convert bf16 -> LDS (XOR slots) ----
    {
        const int row = tid >> 4, q16 = tid & 15;
        const int lab = labels[b * Ldim + l0 + row];
        const float4* src = (const float4*)(table + (size_t)lab * Hdim + q16 * 16);
        float4 f0 = src[0], f1 = src[1], f2 = src[2], f3 = src[3];
        const int s0 = q16 * 2;
        *(short8*)&qt[row][((s0) ^ (row & 15)) * 8] = pack8(f0, f1);
        *(short8*)&qt[row][((s0 + 1) ^ (row & 15)) * 8] = pack8(f2, f3);
    }
    __syncthreads();  // Q visible; K chunk 0 landed (barrier drains vmem)

    // ---- Phase A: S-strip (32 l x 128 t) per wave; m97-style dbuf pipeline ----
    floatx16 acc[4];
#pragma unroll
    for (int nt = 0; nt < 4; nt++)
#pragma unroll
        for (int r = 0; r < 16; r++) acc[nt][r] = 0.f;
#pragma unroll
    for (int hc = 0; hc < 16; hc++) {
        if (hc) __syncthreads();               // chunk hc landed; prev buf reads retired
        if (hc < 15) {
#pragma unroll
            for (int j = 0; j < 4; j++)        // prefetch chunk hc+1; lands during compute
                gload_lds16(ksrc + (hc + 1) * 16 + j * 32 * Hdim,
                            &stage[wave][(hc + 1) & 1][j * 512]);
        }
        const ushort* kw = &stage[wave][hc & 1][0];
        short8 af = *(const short8*)&qt[m][((hc * 2 + half) ^ (m & 15)) * 8];
        short8 b0 = *(const short8*)&kw[(0 * 64 + half * 32 + m) * 8];
        short8 b1 = *(const short8*)&kw[(1 * 64 + half * 32 + m) * 8];
        short8 b2 = *(const short8*)&kw[(2 * 64 + half * 32 + m) * 8];
        short8 b3 = *(const short8*)&kw[(3 * 64 + half * 32 + m) * 8];
        acc[0] = __builtin_amdgcn_mfma_f32_32x32x16_bf16(af, b0, acc[0], 0, 0, 0);
        acc[1] = __builtin_amdgcn_mfma_f32_32x32x16_bf16(af, b1, acc[1], 0, 0, 0);
        acc[2] = __builtin_amdgcn_mfma_f32_32x32x16_bf16(af, b2, acc[2], 0, 0, 0);
        acc[3] = __builtin_amdgcn_mfma_f32_32x32x16_bf16(af, b3, acc[3], 0, 0, 0);
    }

    // ---- issue V chunk 0 DMA now: hides under the softmax VALU block ----
    // V chunk vc: this wave's [32h][64t]. inst j, lane l: h = wave*32+(l&31),
    // t = vc*64+(j*2+(l>>5))*8. dest slot = j*64+l. Frag (ts,half) = slot
    // (ts*2+half)*32+m -> 32 consecutive slots: conflict-free.
    const ushort* vsrc =
        vt + ((size_t)(b * Hdim + wave * 32 + (lane & 31))) * Tdim + (lane >> 5) * 8;
#pragma unroll
    for (int j = 0; j < 4; j++) gload_lds16(vsrc + j * 16, &stage[wave][0][j * 512]);

    // ---- exp + per-row sums. 32x32 C/D: row=(r&3)+8*(r>>2)+4*half, col=m ----
    float rs[16];
#pragma unroll
    for (int nt = 0; nt < 4; nt++)
#pragma unroll
        for (int r = 0; r < 16; r++) {
            float e = __expf(acc[nt][r]);
            acc[nt][r] = e;
            if (nt == 0) rs[r] = e; else rs[r] += e;
        }
#pragma unroll
    for (int s = 1; s < 32; s <<= 1)
#pragma unroll
        for (int r = 0; r < 16; r++) rs[r] += __shfl_xor(rs[r], s, 64);

    // ---- pack exp(S) to bf16 pairs: pk[p][r] = {bf16(acc[2p][r]), bf16(acc[2p+1][r])} ----
    unsigned pk[2][16];
#pragma unroll
    for (int p = 0; p < 2; p++)
#pragma unroll
        for (int r = 0; r < 16; r++)
            pk[p][r] = (unsigned)f2bf(acc[2 * p][r]) |
                       ((unsigned)f2bf(acc[2 * p + 1][r]) << 16);

    __syncthreads();  // Phase A done everywhere: Q region dead -> stats writable
    if (m == 0) {
#pragma unroll
        for (int r = 0; r < 16; r++) sc[wave * 32 + (r & 3) + 8 * (r >> 2) + 4 * half] = rs[r];
    }
    __syncthreads();
    if (tid < 32) {
        float d = 0.f;
#pragma unroll
        for (int wv = 0; wv < 8; wv++) d += sc[wv * 32 + tid];
        rinv[tid] = 1.0f / d;
    }
    __syncthreads();  // rinv visible; V chunk 0 long since landed

    // P chunk c (64t) = strip-half c&1 of wave c>>1; buffer = pk part = c&1.
    // Element (row, t=q*32+m): slot (q*4+(m>>3))^(row&7), byte elem m&7.
    auto write_chunk = [&](int c) {
        const int bi = c & 1;
        ushort* dst = p2 + bi * 2048;
#pragma unroll
        for (int q = 0; q < 2; q++)
#pragma unroll
            for (int r = 0; r < 16; r++) {
                const int row = (r & 3) + 8 * (r >> 2) + 4 * half;
                const ushort e = q ? (ushort)(pk[bi][r] >> 16) : (ushort)(pk[bi][r] & 0xffffu);
                dst[row * 64 + (((q * 4 + (m >> 3)) ^ (row & 7)) << 3) + (m & 7)] = e;
            }
    };
    if (wave == 0) write_chunk(0);

    // ---- attention out: straight from registers, normalized dword stores ----
    {
        float inv[16];
#pragma unroll
        for (int r = 0; r < 16; r++) inv[r] = rinv[(r & 3) + 8 * (r >> 2) + 4 * half];
        float* dst = attn_out + ((size_t)(b * Ldim + l0)) * Tdim + wave * 128 + m;
#pragma unroll
        for (int p = 0; p < 2; p++)
#pragma unroll
            for (int r = 0; r < 16; r++) {
                const int row = (r & 3) + 8 * (r >> 2) + 4 * half;
                dst[(size_t)row * Tdim + (2 * p) * 32] =
                    bf2f((ushort)(pk[p][r] & 0xffffu)) * inv[r];
                dst[(size_t)row * Tdim + (2 * p + 1) * 32] =
                    bf2f((ushort)(pk[p][r] >> 16)) * inv[r];
            }
    }
    __syncthreads();  // P chunk 0 visible; attn stores + strip writes drained

    // ---- Phase C: logits = P.V; 16 steps of 64t; m97-style dbuf pipeline ----
    floatx16 c0, c1;
#pragma unroll
    for (int r = 0; r < 16; r++) { c0[r] = 0.f; c1[r] = 0.f; }
#pragma unroll
    for (int vc = 0; vc < 16; vc++) {
        if (vc) __syncthreads();               // V chunk vc + P chunk vc landed/visible
        if (vc < 15) {
#pragma unroll
            for (int j = 0; j < 4; j++)        // prefetch V chunk vc+1
                gload_lds16(vsrc + (vc + 1) * 64 + j * 16,
                            &stage[wave][(vc + 1) & 1][j * 512]);
            if (((vc + 1) >> 1) == wave) write_chunk(vc + 1);  // produce next P chunk
        }
        const ushort* pw = p2 + (vc & 1) * 2048;
        const ushort* vw = &stage[wave][vc & 1][0];
#pragma unroll
        for (int ts = 0; ts < 4; ts++) {
            short8 a = *(const short8*)&pw[m * 64 + (((ts * 2 + half) ^ (m & 7)) << 3)];
            short8 v = *(const short8*)&vw[((ts * 2 + half) * 32 + m) * 8];
            if (ts & 1) c1 = __builtin_amdgcn_mfma_f32_32x32x16_bf16(a, v, c1, 0, 0, 0);
            else        c0 = __builtin_amdgcn_mfma_f32_32x32x16_bf16(a, v, c0, 0, 0, 0);
        }
    }

#pragma unroll
    for (int r = 0; r < 16; r++) {
        const int row = (r & 3) + 8 * (r >> 2) + 4 * half;
        logits_out[((size_t)(b * Ldim + l0 + row)) * Hdim + wave * 32 + m] =
            (c0[r] + c1[r]) * rinv[row];
    }
}

extern "C" void kernel_launch(void* const* d_in, const int* in_sizes, int n_in,
                              void* d_out, int out_size, void* d_ws, size_t ws_size,
                              hipStream_t stream) {
    const float* inputs = (const float*)d_in[0];   // (B,T,H) fp32
    const int* labels   = (const int*)d_in[1];     // (B,L)
    const float* table  = (const float*)d_in[2];   // (NC+1,H) fp32
    float* out = (float*)d_out;

    ushort* kn = (ushort*)d_ws;                    // bf16 (B,T,H)
    ushort* vt = kn + (size_t)Bdim * Tdim * Hdim;  // bf16 (B,H,T)

    convert_kernel<<<dim3(Tdim / 64, Hdim / 64, Bdim), 256, 0, stream>>>(inputs, kn, vt);

    float* logits_out = out;
    float* attn_out = out + (size_t)Bdim * Ldim * Hdim;
    attn_kernel<<<Bdim * (Ldim / 32), 512, 0, stream>>>(table, labels, kn, vt,
                                                        logits_out, attn_out);
}